// Round 15
// baseline (721.985 us; speedup 1.0000x reference)
//
#include <hip/hip_runtime.h>
#include <math.h>

typedef short bf16x8 __attribute__((ext_vector_type(8)));
typedef float f32x4 __attribute__((ext_vector_type(4)));
typedef int   i32x4 __attribute__((ext_vector_type(4)));

#define HH 8
#define NN 4096
#define DIP 256   // ip(240) + s(16) as int8, no pad
#define DDX 256   // qdx bf16: [hi|hi | mid|lo | mid32-47+16z | hi32-47+16z]
#define DKM 192   // kmx bf16: [mid | lo | hi | hi]
#define DV 272
#define BN 32
#define NT (NN/BN)

typedef const __attribute__((address_space(1))) unsigned int* gp_t;
typedef __attribute__((address_space(3))) unsigned int* lp_t;
__device__ __forceinline__ void gload16(const void* g, void* l) {
    __builtin_amdgcn_global_load_lds((gp_t)g, (lp_t)l, 16, 0, 0);
}

__device__ __forceinline__ unsigned short f2bf(float f) {
    unsigned int u = __float_as_uint(f);
    u = (u + 0x7fffu + ((u >> 16) & 1u)) >> 16;   // RNE
    return (unsigned short)u;
}
__device__ __forceinline__ float bf2f(unsigned short h) {
    return __uint_as_float(((unsigned int)h) << 16);
}
__device__ __forceinline__ float fexp2(float x) {   // 2^x, single v_exp_f32
    float r;
    asm("v_exp_f32 %0, %1" : "=v"(r) : "v"(x));
    return r;
}
__device__ __forceinline__ signed char q8(float x) {  // i8 quant, scale 127/6 (±6 sigma)
    int v = __float2int_rn(x * 21.1666667f);
    v = v < -127 ? -127 : (v > 127 ? 127 : v);
    return (signed char)v;
}

#define MFMA16(A,B,C) __builtin_amdgcn_mfma_f32_16x16x32_bf16((A),(B),(C),0,0,0)
#define MFMAI8(A,B,C) __builtin_amdgcn_mfma_i32_16x16x64_i8((A),(B),(C),0,0,0)

// ---- stage 1a: features. fip[256] = ip+s as i8. fdx bf16: Q-mode 256 / K-mode 192 ----
__global__ void feat_kernel(const float* __restrict__ mv,
                            const float* __restrict__ sv,
                            const float* __restrict__ basis,
                            float scale, int qmode,
                            signed char* __restrict__ fip,
                            unsigned short* __restrict__ fdx)
{
    __shared__ float sb[150];
    int t = threadIdx.x;
    if (t < 150) sb[t] = basis[t];
    __syncthreads();
    int row = blockIdx.x * 32 + (t >> 3);   // (h*4096+n)
    int c = t & 7;
    const float* m = mv + (size_t)row * 256 + c * 32;
    float f[32];
    #pragma unroll
    for (int i = 0; i < 8; ++i) {
        float4 v = ((const float4*)m)[i];
        f[i*4+0] = v.x; f[i*4+1] = v.y; f[i*4+2] = v.z; f[i*4+3] = v.w;
    }
    signed char* ip = fip + (size_t)row * DIP;
    unsigned short* dx = fdx + (size_t)row * (qmode ? DDX : DKM);
    #pragma unroll
    for (int j = 0; j < 30; ++j)
        ip[c*30 + j] = q8(f[1+j]);
    if (c < 2) {
        #pragma unroll
        for (int i = 0; i < 8; ++i)
            ip[240 + c*8 + i] = q8(sv[(size_t)row*16 + c*8 + i]);
    }
    float nn = 1.0f / sqrtf(f[5]*f[5] + 0.001f);
    float tn[5];
    #pragma unroll
    for (int x = 0; x < 5; ++x) tn[x] = f[1+x] * nn;
    #pragma unroll
    for (int z = 0; z < 6; ++z) {
        float acc = 0.f;
        #pragma unroll
        for (int x = 0; x < 5; ++x) {
            #pragma unroll
            for (int y = 0; y < 5; ++y)
                acc = fmaf(sb[(x*5+y)*6 + z] * tn[x], tn[y], acc);
        }
        acc *= scale;
        unsigned short hi = f2bf(acc);
        float r1 = acc - bf2f(hi);
        unsigned short mi = f2bf(r1);
        float r2 = r1 - bf2f(mi);
        unsigned short lo = f2bf(r2);
        int cz = c*6 + z;
        if (qmode) {
            dx[cz]      = hi;  dx[48 + cz]  = hi;
            dx[96 + cz] = mi;  dx[144 + cz] = lo;
            if (cz < 16) { dx[208 + cz] = 0; dx[240 + cz] = 0; }
            if (cz >= 32) { dx[160 + cz] = mi; dx[192 + cz] = hi; }
        } else {
            dx[cz]      = mi;  dx[48 + cz]  = lo;
            dx[96 + cz] = hi;  dx[144 + cz] = hi;
        }
    }
}

// ---- stage 1b: V -> transposed bf16 [8][272][4096] ----
__global__ void vtrans_kernel(const float* __restrict__ vmv,
                              const float* __restrict__ vs,
                              unsigned short* __restrict__ dst)
{
    __shared__ unsigned short tile[64][DV];
    int blk = blockIdx.x;
    int h = blk >> 6;
    int n0 = (blk & 63) << 6;
    int t = threadIdx.x;
    #pragma unroll
    for (int it = 0; it < 16; ++it) {
        int v = t + it*256;
        int r = v >> 6;
        int sg = v & 63;
        float4 x = *(const float4*)(vmv + ((size_t)(h*NN + n0 + r))*256 + sg*4);
        tile[r][sg*4+0] = f2bf(x.x);
        tile[r][sg*4+1] = f2bf(x.y);
        tile[r][sg*4+2] = f2bf(x.z);
        tile[r][sg*4+3] = f2bf(x.w);
    }
    #pragma unroll
    for (int it = 0; it < 4; ++it) {
        int v = t + it*256;
        int r = v >> 4;
        int si = v & 15;
        tile[r][256 + si] = f2bf(vs[((size_t)(h*NN + n0 + r))*16 + si]);
    }
    __syncthreads();
    #pragma unroll
    for (int it = 0; it < 17; ++it) {
        int v = t + it*256;
        int dd = v >> 4;
        int sg = v & 15;
        ushort4 o;
        o.x = tile[sg*4+0][dd];
        o.y = tile[sg*4+1][dd];
        o.z = tile[sg*4+2][dd];
        o.w = tile[sg*4+3][dd];
        *(ushort4*)(dst + ((size_t)(h*DV + dd))*NN + n0 + sg*4) = o;
    }
}

// ---- stage 2: flash attention, 4 fat waves x 32 q, BN=32, 2 blocks/CU ----
__global__ __launch_bounds__(256, 2)
void attn_kernel(const signed char*    __restrict__ Qip,
                 const unsigned short* __restrict__ Qdx,
                 const signed char*    __restrict__ Kip,
                 const unsigned short* __restrict__ Kmx,
                 const unsigned short* __restrict__ Vt,
                 float* __restrict__ out)
{
    // bytes: kt 2x8192 [0,16384) | kmx 2x12288 [16384,40960) | vt 17408 [40960,58368) | pb 8192 [58368,66560)
    __shared__ __align__(128) unsigned short smem[33280];   // 66,560 B -> 2 blocks/CU

    int blk = blockIdx.x;
    int sbk = ((blk & 7) << 5) | (blk >> 3);   // grid 256, bijective XCD swizzle; XCD x = head x
    int h = sbk >> 5;
    int q0 = (sbk & 31) * 128;
    int tid = threadIdx.x;
    int w = tid >> 6;                          // 4 waves, wave owns q rows [q0+w*32, q0+w*32+32)
    int lane = tid & 63;
    int l15 = lane & 15;
    int l4 = lane >> 4;
    int l7l = l15 & 3;
    int l7h = (l15 >> 2) & 1;
    int x7 = l15 & 7;

    // Q ip fragments (i8, B-operand), two q-halves
    const signed char* qipr = Qip + (size_t)(h*NN + q0 + w*32 + l15) * DIP + l4*16;
    i32x4 qip[4][2];
    #pragma unroll
    for (int s = 0; s < 4; ++s) {
        qip[s][0] = *(const i32x4*)(qipr + s*64);
        qip[s][1] = *(const i32x4*)(qipr + 16*DIP + s*64);
    }
    // Q dist fragments (bf16, dup-block), two q-halves
    const unsigned short* qdxr = Qdx + (size_t)(h*NN + q0 + w*32 + l15) * DDX + l4*8;
    bf16x8 qdx[8][2];
    #pragma unroll
    for (int ks = 0; ks < 8; ++ks) {
        qdx[ks][0] = *(const bf16x8*)(qdxr + ks*32);
        qdx[ks][1] = *(const bf16x8*)(qdxr + 16*DDX + ks*32);
    }

    // LDS read bases (bytes) — r12-verified formulas
    int cl16 = (l4 ^ l7l) * 16;
    int mA  = l15*384 + cl16 + l7h*64;
    int mB  = l15*384 + cl16 + 64 - l7h*64;
    int kti[4];
    #pragma unroll
    for (int s = 0; s < 4; ++s)
        kti[s] = l15*256 + (((s*4 + l4) ^ x7) << 4);
    int vlane = (l15>>1)*128 + (((((l15&1)<<2) | l4) ^ (l15>>1)) << 4);
    int pbW = 58368 + w*2048 + l15*64;              // qh0; qh1 = +1024
    int pSeg0 = pbW + ((((l4>>1)    ) ^ l7l) << 4) + (l4&1)*8;
    int pSeg1 = pbW + ((((l4>>1) + 2) ^ l7l) << 4) + (l4&1)*8;
    int pRd   = pbW + ((l4 ^ l7l) << 4);

    // DMA source offsets, loop-invariant (256-thread slot maps)
    int kts0, kts1;                       // Kip bytes (512 slots)
    { int s_ = tid;     int r_ = s_>>4, sg_ = s_&15; kts0 = r_*256 + ((sg_ ^ (r_&7))<<4); }
    { int s_ = tid+256; int r_ = s_>>4, sg_ = s_&15; kts1 = r_*256 + ((sg_ ^ (r_&7))<<4); }
    int kms0, kms1, kms2;                 // Kmx ush (768 slots)
#define KMFL(SLOT, DST) { int r_ = (SLOT)/24, fp_ = (SLOT)%24; \
    int g_ = fp_>>3, po_ = fp_&7; \
    int pl_ = ((((po_>>2)&1) ^ ((r_>>2)&1)) << 2) | ((po_&3) ^ (r_&3)); \
    DST = r_*DKM + (g_*8 + pl_)*8; }
    KMFL(tid, kms0) KMFL(tid+256, kms1) KMFL(tid+512, kms2)
#undef KMFL
    int vts0, vts1, vts2, vts3, vts4;     // Vt ush (1088 slots)
#define VTF(SLOT, DST) { int ch_ = (SLOT) >> 3, ws_ = (SLOT) & 7; int lw_ = ws_ ^ (ch_&7); \
    DST = (ch_*2 + (lw_>>2))*NN + (lw_&3)*8; }
    VTF(tid, vts0) VTF(tid+256, vts1) VTF(tid+512, vts2) VTF(tid+768, vts3) VTF(tid+1024, vts4)
#undef VTF

    const signed char*    kiph = Kip + (size_t)h*NN*DIP;
    const unsigned short* kmxh = Kmx + (size_t)h*NN*DKM;
    const unsigned short* vh   = Vt  + (size_t)h*DV*NN;

    f32x4 zero = {0.f, 0.f, 0.f, 0.f};
    i32x4 zi = {0, 0, 0, 0};
    f32x4 oacc[17][2];                    // [dim-tile][q-half]
    #pragma unroll
    for (int ct = 0; ct < 17; ++ct) { oacc[ct][0] = zero; oacc[ct][1] = zero; }
    float m0 = -__builtin_inff(), l0 = 0.f;
    float m1 = -__builtin_inff(), l1 = 0.f;
    const float F = 0.08274443827037988f * (6.0f/127.0f) * (6.0f/127.0f);

    // K staging: 5 loads/thread (uniform). V staging: wave0: 5, waves1-3: 4.
#define ISSUE_K(TILE, BUF) do { \
    const signed char* ks_ = kiph + (size_t)(TILE)*BN*DIP; \
    const unsigned short* ms_ = kmxh + (size_t)(TILE)*BN*DKM; \
    char* ktd_ = (char*)smem + (BUF)*8192; \
    char* kmd_ = (char*)smem + 16384 + (BUF)*12288; \
    gload16(ks_ + kts0, ktd_ + tid*16); \
    gload16(ks_ + kts1, ktd_ + (tid+256)*16); \
    gload16(ms_ + kms0, kmd_ + tid*16); \
    gload16(ms_ + kms1, kmd_ + (tid+256)*16); \
    gload16(ms_ + kms2, kmd_ + (tid+512)*16); \
} while (0)

#define ISSUE_V(TILE) do { \
    const unsigned short* vs_ = vh + (TILE)*BN; \
    char* vtd_ = (char*)smem + 40960; \
    gload16(vs_ + vts0, vtd_ + tid*16); \
    gload16(vs_ + vts1, vtd_ + (tid+256)*16); \
    gload16(vs_ + vts2, vtd_ + (tid+512)*16); \
    gload16(vs_ + vts3, vtd_ + (tid+768)*16); \
    if (tid < 64) gload16(vs_ + vts4, vtd_ + (tid+1024)*16); \
} while (0)

    ISSUE_K(0, 0);
    int cur = 0;
    #pragma unroll 1
    for (int t = 0; t < NT; ++t) {
        ISSUE_V(t);                          // vt free: BAR3(t-1) passed
        if (t < NT-1) {
            ISSUE_K(t+1, cur^1);             // kt/kmx(t-1) buffer free since QKT(t-1)
            if (w == 0) asm volatile("s_waitcnt vmcnt(10)" ::: "memory");
            else        asm volatile("s_waitcnt vmcnt(9)"  ::: "memory");
        } else {
            if (w == 0) asm volatile("s_waitcnt vmcnt(5)" ::: "memory");
            else        asm volatile("s_waitcnt vmcnt(4)" ::: "memory");
        }
        __builtin_amdgcn_sched_barrier(0);
        __builtin_amdgcn_s_barrier();        // BAR1: K tile t visible
        __builtin_amdgcn_sched_barrier(0);

        const char* ktb = (const char*)smem + cur*8192;
        const char* kmb = (const char*)smem + 16384 + cur*12288;

        // ---- QKT: i8 part (A-frag read once, used by both q-halves) ----
        i32x4 si00 = zi, si01 = zi, si10 = zi, si11 = zi;   // [key-tile][q-half]
        __builtin_amdgcn_s_setprio(1);
        #pragma unroll
        for (int s = 0; s < 4; ++s) {
            i32x4 a0 = *(const i32x4*)(ktb + kti[s]);          // keys 0-15
            i32x4 a1 = *(const i32x4*)(ktb + 4096 + kti[s]);   // keys 16-31
            si00 = MFMAI8(a0, qip[s][0], si00);
            si01 = MFMAI8(a0, qip[s][1], si01);
            si10 = MFMAI8(a1, qip[s][0], si10);
            si11 = MFMAI8(a1, qip[s][1], si11);
        }
        // convert i8 scores -> f32 C-init for the dist chains (frees si regs)
        f32x4 sn00, sn01, sn10, sn11;
        #pragma unroll
        for (int j = 0; j < 4; ++j) {
            sn00[j] = F * (float)si00[j];
            sn01[j] = F * (float)si01[j];
            sn10[j] = F * (float)si10[j];
            sn11[j] = F * (float)si11[j];
        }
        {   // dist split-precision, key-tile 0
            const char* kk = kmb;
            bf16x8 ka0 = *(const bf16x8*)(kk + mA);
            bf16x8 ka1 = *(const bf16x8*)(kk + mB);
            bf16x8 ka2 = *(const bf16x8*)(kk + mA + 128);
            bf16x8 kb0 = *(const bf16x8*)(kk + mB + 128);
            bf16x8 kb1 = *(const bf16x8*)(kk + mA + 256);
            bf16x8 kb2 = *(const bf16x8*)(kk + mB + 256);
            sn00 = MFMA16(ka0, qdx[0][0], sn00);  sn01 = MFMA16(ka0, qdx[0][1], sn01);
            sn00 = MFMA16(ka1, qdx[1][0], sn00);  sn01 = MFMA16(ka1, qdx[1][1], sn01);
            sn00 = MFMA16(ka2, qdx[2][0], sn00);  sn01 = MFMA16(ka2, qdx[2][1], sn01);
            sn00 = MFMA16(kb0, qdx[3][0], sn00);  sn01 = MFMA16(kb0, qdx[3][1], sn01);
            sn00 = MFMA16(kb1, qdx[4][0], sn00);  sn01 = MFMA16(kb1, qdx[4][1], sn01);
            sn00 = MFMA16(kb2, qdx[5][0], sn00);  sn01 = MFMA16(kb2, qdx[5][1], sn01);
            sn00 = MFMA16(ka0, qdx[3][0], sn00);  sn01 = MFMA16(ka0, qdx[3][1], sn01);
            sn00 = MFMA16(ka1, qdx[6][0], sn00);  sn01 = MFMA16(ka1, qdx[6][1], sn01);
            sn00 = MFMA16(kb0, qdx[0][0], sn00);  sn01 = MFMA16(kb0, qdx[0][1], sn01);
            sn00 = MFMA16(kb1, qdx[7][0], sn00);  sn01 = MFMA16(kb1, qdx[7][1], sn01);
        }
        {   // dist split-precision, key-tile 1
            const char* kk = kmb + 6144;
            bf16x8 ka0 = *(const bf16x8*)(kk + mA);
            bf16x8 ka1 = *(const bf16x8*)(kk + mB);
            bf16x8 ka2 = *(const bf16x8*)(kk + mA + 128);
            bf16x8 kb0 = *(const bf16x8*)(kk + mB + 128);
            bf16x8 kb1 = *(const bf16x8*)(kk + mA + 256);
            bf16x8 kb2 = *(const bf16x8*)(kk + mB + 256);
            sn10 = MFMA16(ka0, qdx[0][0], sn10);  sn11 = MFMA16(ka0, qdx[0][1], sn11);
            sn10 = MFMA16(ka1, qdx[1][0], sn10);  sn11 = MFMA16(ka1, qdx[1][1], sn11);
            sn10 = MFMA16(ka2, qdx[2][0], sn10);  sn11 = MFMA16(ka2, qdx[2][1], sn11);
            sn10 = MFMA16(kb0, qdx[3][0], sn10);  sn11 = MFMA16(kb0, qdx[3][1], sn11);
            sn10 = MFMA16(kb1, qdx[4][0], sn10);  sn11 = MFMA16(kb1, qdx[4][1], sn11);
            sn10 = MFMA16(kb2, qdx[5][0], sn10);  sn11 = MFMA16(kb2, qdx[5][1], sn11);
            sn10 = MFMA16(ka0, qdx[3][0], sn10);  sn11 = MFMA16(ka0, qdx[3][1], sn11);
            sn10 = MFMA16(ka1, qdx[6][0], sn10);  sn11 = MFMA16(ka1, qdx[6][1], sn11);
            sn10 = MFMA16(kb0, qdx[0][0], sn10);  sn11 = MFMA16(kb0, qdx[0][1], sn11);
            sn10 = MFMA16(kb1, qdx[7][0], sn10);  sn11 = MFMA16(kb1, qdx[7][1], sn11);
        }
        __builtin_amdgcn_s_setprio(0);

        // ---- online softmax, both q-halves (independent m/l); defer-max THR=8 ----
        float pm0 = fmaxf(fmaxf(fmaxf(sn00[0], sn00[1]), fmaxf(sn00[2], sn00[3])),
                          fmaxf(fmaxf(sn10[0], sn10[1]), fmaxf(sn10[2], sn10[3])));
        float pm1 = fmaxf(fmaxf(fmaxf(sn01[0], sn01[1]), fmaxf(sn01[2], sn01[3])),
                          fmaxf(fmaxf(sn11[0], sn11[1]), fmaxf(sn11[2], sn11[3])));
        pm0 = fmaxf(pm0, __shfl_xor(pm0, 16, 64));
        pm0 = fmaxf(pm0, __shfl_xor(pm0, 32, 64));
        pm1 = fmaxf(pm1, __shfl_xor(pm1, 16, 64));
        pm1 = fmaxf(pm1, __shfl_xor(pm1, 32, 64));
        bool ok0 = __all(pm0 <= m0 + 8.0f);
        bool ok1 = __all(pm1 <= m1 + 8.0f);
        if (!(ok0 && ok1)) {
            float mn0 = fmaxf(m0, pm0), mn1 = fmaxf(m1, pm1);
            float al0 = fexp2(m0 - mn0), al1 = fexp2(m1 - mn1);   // 1 when that half fine
            m0 = mn0; m1 = mn1;
            l0 *= al0; l1 *= al1;
            float a00 = __shfl(al0, l4*4+0, 64), a01 = __shfl(al0, l4*4+1, 64);
            float a02 = __shfl(al0, l4*4+2, 64), a03 = __shfl(al0, l4*4+3, 64);
            float a10 = __shfl(al1, l4*4+0, 64), a11 = __shfl(al1, l4*4+1, 64);
            float a12 = __shfl(al1, l4*4+2, 64), a13 = __shfl(al1, l4*4+3, 64);
            #pragma unroll
            for (int ct = 0; ct < 17; ++ct) {
                oacc[ct][0][0] *= a00; oacc[ct][0][1] *= a01;
                oacc[ct][0][2] *= a02; oacc[ct][0][3] *= a03;
                oacc[ct][1][0] *= a10; oacc[ct][1][1] *= a11;
                oacc[ct][1][2] *= a12; oacc[ct][1][3] *= a13;
            }
        }
        char* pbp = (char*)smem;
        {   // P for q-half 0
            float p0 = fexp2(sn00[0] - m0), p1 = fexp2(sn00[1] - m0);
            float p2 = fexp2(sn00[2] - m0), p3 = fexp2(sn00[3] - m0);
            float p4 = fexp2(sn10[0] - m0), p5 = fexp2(sn10[1] - m0);
            float p6 = fexp2(sn10[2] - m0), p7 = fexp2(sn10[3] - m0);
            l0 += ((p0 + p1) + (p2 + p3)) + ((p4 + p5) + (p6 + p7));
            unsigned r01, r23, r45, r67;
            asm("v_cvt_pk_bf16_f32 %0, %1, %2" : "=v"(r01) : "v"(p0), "v"(p1));
            asm("v_cvt_pk_bf16_f32 %0, %1, %2" : "=v"(r23) : "v"(p2), "v"(p3));
            asm("v_cvt_pk_bf16_f32 %0, %1, %2" : "=v"(r45) : "v"(p4), "v"(p5));
            asm("v_cvt_pk_bf16_f32 %0, %1, %2" : "=v"(r67) : "v"(p6), "v"(p7));
            *(unsigned long long*)(pbp + pSeg0) = ((unsigned long long)r23 << 32) | r01;
            *(unsigned long long*)(pbp + pSeg1) = ((unsigned long long)r67 << 32) | r45;
        }
        {   // P for q-half 1
            float p0 = fexp2(sn01[0] - m1), p1 = fexp2(sn01[1] - m1);
            float p2 = fexp2(sn01[2] - m1), p3 = fexp2(sn01[3] - m1);
            float p4 = fexp2(sn11[0] - m1), p5 = fexp2(sn11[1] - m1);
            float p6 = fexp2(sn11[2] - m1), p7 = fexp2(sn11[3] - m1);
            l1 += ((p0 + p1) + (p2 + p3)) + ((p4 + p5) + (p6 + p7));
            unsigned r01, r23, r45, r67;
            asm("v_cvt_pk_bf16_f32 %0, %1, %2" : "=v"(r01) : "v"(p0), "v"(p1));
            asm("v_cvt_pk_bf16_f32 %0, %1, %2" : "=v"(r23) : "v"(p2), "v"(p3));
            asm("v_cvt_pk_bf16_f32 %0, %1, %2" : "=v"(r45) : "v"(p4), "v"(p5));
            asm("v_cvt_pk_bf16_f32 %0, %1, %2" : "=v"(r67) : "v"(p6), "v"(p7));
            *(unsigned long long*)(pbp + pSeg0 + 1024) = ((unsigned long long)r23 << 32) | r01;
            *(unsigned long long*)(pbp + pSeg1 + 1024) = ((unsigned long long)r67 << 32) | r45;
        }

        // drain V(t): remaining in flight = K(t+1) (5) or nothing on last iter
        if (t < NT-1) asm volatile("s_waitcnt vmcnt(5)" ::: "memory");
        else          asm volatile("s_waitcnt vmcnt(0)" ::: "memory");
        __builtin_amdgcn_sched_barrier(0);
        __builtin_amdgcn_s_barrier();        // BAR2: V tile visible
        __builtin_amdgcn_sched_barrier(0);

        // ---- PV: O += P(32x32) @ V(32x272), B-frag read once per dim-tile ----
        {
            bf16x8 pa0 = *(const bf16x8*)(pbp + pRd);
            bf16x8 pa1 = *(const bf16x8*)(pbp + pRd + 1024);
            const char* vtb = (const char*)smem + 40960;
            __builtin_amdgcn_s_setprio(1);
            #pragma unroll
            for (int ct = 0; ct < 17; ++ct) {
                bf16x8 bv = *(const bf16x8*)(vtb + vlane + ct*1024);
                oacc[ct][0] = MFMA16(pa0, bv, oacc[ct][0]);
                oacc[ct][1] = MFMA16(pa1, bv, oacc[ct][1]);
            }
            __builtin_amdgcn_s_setprio(0);
        }
        __builtin_amdgcn_s_barrier();        // BAR3: all waves done reading vt
        __builtin_amdgcn_sched_barrier(0);
        cur ^= 1;
    }
#undef ISSUE_K
#undef ISSUE_V

    // epilogue: finish deferred l (both halves), scatter
    float lf0 = l0, lf1 = l1;
    lf0 += __shfl_xor(lf0, 16, 64);
    lf0 += __shfl_xor(lf0, 32, 64);
    lf1 += __shfl_xor(lf1, 16, 64);
    lf1 += __shfl_xor(lf1, 32, 64);
    const size_t mv_total = (size_t)HH * NN * 256;
    #pragma unroll
    for (int j = 0; j < 4; ++j) {
        float inv0 = 1.0f / __shfl(lf0, l4*4 + j, 64);
        float inv1 = 1.0f / __shfl(lf1, l4*4 + j, 64);
        int qA = q0 + w*32 + l4*4 + j;
        int qB = qA + 16;
        float* poA = out + ((size_t)h*NN + qA) * 256 + l15;
        float* poB = out + ((size_t)h*NN + qB) * 256 + l15;
        #pragma unroll
        for (int ct = 0; ct < 16; ++ct) {
            poA[ct*16] = oacc[ct][0][j] * inv0;
            poB[ct*16] = oacc[ct][1][j] * inv1;
        }
        out[mv_total + ((size_t)h*NN + qA)*16 + l15] = oacc[16][0][j] * inv0;
        out[mv_total + ((size_t)h*NN + qB)*16 + l15] = oacc[16][1][j] * inv1;
    }
}

extern "C" void kernel_launch(void* const* d_in, const int* in_sizes, int n_in,
                              void* d_out, int out_size, void* d_ws, size_t ws_size,
                              hipStream_t stream)
{
    const float* q_mv = (const float*)d_in[0];
    const float* k_mv = (const float*)d_in[1];
    const float* v_mv = (const float*)d_in[2];
    const float* q_s  = (const float*)d_in[3];
    const float* k_s  = (const float*)d_in[4];
    const float* v_s  = (const float*)d_in[5];
    const float* basis_q = (const float*)d_in[6];
    const float* basis_k = (const float*)d_in[7];
    float* out = (float*)d_out;

    signed char* qip8 = (signed char*)d_ws;                         // [8][4096][256] i8
    signed char* kip8 = qip8 + (size_t)HH*NN*DIP;                   // [8][4096][256] i8
    unsigned short* qdx = (unsigned short*)(kip8 + (size_t)HH*NN*DIP); // [8][4096][256] bf16
    unsigned short* kmx = qdx + (size_t)HH*NN*DDX;                  // [8][4096][192] bf16
    unsigned short* vt  = kmx + (size_t)HH*NN*DKM;                  // [8][272][4096] bf16
    // total ws use: ~64.1 MB

    // 1/sqrt(304) * log2(e): dist features carry it; ip carries it via F in-kernel
    const float qscale = 0.08274443827037988f;

    feat_kernel<<<dim3(1024), dim3(256), 0, stream>>>(q_mv, q_s, basis_q, qscale, 1, qip8, qdx);
    feat_kernel<<<dim3(1024), dim3(256), 0, stream>>>(k_mv, k_s, basis_k, 1.0f,   0, kip8, kmx);
    vtrans_kernel<<<dim3(512), dim3(256), 0, stream>>>(v_mv, v_s, vt);
    attn_kernel<<<dim3(256), dim3(256), 0, stream>>>(qip8, qdx, kip8, kmx, vt, out);
}

// Round 16
// 257.918 us; speedup vs baseline: 2.7993x; 2.7993x over previous
//
#include <hip/hip_runtime.h>
#include <math.h>

typedef short bf16x8 __attribute__((ext_vector_type(8)));
typedef float f32x4 __attribute__((ext_vector_type(4)));
typedef int   i32x4 __attribute__((ext_vector_type(4)));

#define HH 8
#define NN 4096
#define DIP 256   // ip(240) + s(16) as int8, no pad
#define DDX 256   // qdx bf16: [hi|hi | mid|lo | mid32-47+16z | hi32-47+16z]
#define DKM 192   // kmx bf16: [mid | lo | hi | hi]
#define DV 272
#define BN 64
#define NT (NN/BN)

typedef const __attribute__((address_space(1))) unsigned int* gp_t;
typedef __attribute__((address_space(3))) unsigned int* lp_t;
__device__ __forceinline__ void gload16(const void* g, void* l) {
    __builtin_amdgcn_global_load_lds((gp_t)g, (lp_t)l, 16, 0, 0);
}

__device__ __forceinline__ unsigned short f2bf(float f) {
    unsigned int u = __float_as_uint(f);
    u = (u + 0x7fffu + ((u >> 16) & 1u)) >> 16;   // RNE
    return (unsigned short)u;
}
__device__ __forceinline__ float bf2f(unsigned short h) {
    return __uint_as_float(((unsigned int)h) << 16);
}
__device__ __forceinline__ float fexp2(float x) {   // 2^x, single v_exp_f32
    float r;
    asm("v_exp_f32 %0, %1" : "=v"(r) : "v"(x));
    return r;
}
__device__ __forceinline__ signed char q8(float x) {  // i8 quant, scale 127/6 (±6 sigma)
    int v = __float2int_rn(x * 21.1666667f);
    v = v < -127 ? -127 : (v > 127 ? 127 : v);
    return (signed char)v;
}

#define MFMA16(A,B,C) __builtin_amdgcn_mfma_f32_16x16x32_bf16((A),(B),(C),0,0,0)
#define MFMAI8(A,B,C) __builtin_amdgcn_mfma_i32_16x16x64_i8((A),(B),(C),0,0,0)

// ---- stage 1a: features. fip[256] = ip+s as i8. fdx bf16: Q-mode 256 / K-mode 192 ----
__global__ void feat_kernel(const float* __restrict__ mv,
                            const float* __restrict__ sv,
                            const float* __restrict__ basis,
                            float scale, int qmode,
                            signed char* __restrict__ fip,
                            unsigned short* __restrict__ fdx)
{
    __shared__ float sb[150];
    int t = threadIdx.x;
    if (t < 150) sb[t] = basis[t];
    __syncthreads();
    int row = blockIdx.x * 32 + (t >> 3);   // (h*4096+n)
    int c = t & 7;
    const float* m = mv + (size_t)row * 256 + c * 32;
    float f[32];
    #pragma unroll
    for (int i = 0; i < 8; ++i) {
        float4 v = ((const float4*)m)[i];
        f[i*4+0] = v.x; f[i*4+1] = v.y; f[i*4+2] = v.z; f[i*4+3] = v.w;
    }
    signed char* ip = fip + (size_t)row * DIP;
    unsigned short* dx = fdx + (size_t)row * (qmode ? DDX : DKM);
    #pragma unroll
    for (int j = 0; j < 30; ++j)
        ip[c*30 + j] = q8(f[1+j]);
    if (c < 2) {
        #pragma unroll
        for (int i = 0; i < 8; ++i)
            ip[240 + c*8 + i] = q8(sv[(size_t)row*16 + c*8 + i]);
    }
    float nn = 1.0f / sqrtf(f[5]*f[5] + 0.001f);
    float tn[5];
    #pragma unroll
    for (int x = 0; x < 5; ++x) tn[x] = f[1+x] * nn;
    #pragma unroll
    for (int z = 0; z < 6; ++z) {
        float acc = 0.f;
        #pragma unroll
        for (int x = 0; x < 5; ++x) {
            #pragma unroll
            for (int y = 0; y < 5; ++y)
                acc = fmaf(sb[(x*5+y)*6 + z] * tn[x], tn[y], acc);
        }
        acc *= scale;
        unsigned short hi = f2bf(acc);
        float r1 = acc - bf2f(hi);
        unsigned short mi = f2bf(r1);
        float r2 = r1 - bf2f(mi);
        unsigned short lo = f2bf(r2);
        int cz = c*6 + z;
        if (qmode) {
            dx[cz]      = hi;  dx[48 + cz]  = hi;
            dx[96 + cz] = mi;  dx[144 + cz] = lo;
            if (cz < 16) { dx[208 + cz] = 0; dx[240 + cz] = 0; }
            if (cz >= 32) { dx[160 + cz] = mi; dx[192 + cz] = hi; }
        } else {
            dx[cz]      = mi;  dx[48 + cz]  = lo;
            dx[96 + cz] = hi;  dx[144 + cz] = hi;
        }
    }
}

// ---- stage 1b: V -> transposed bf16 [8][272][4096] ----
__global__ void vtrans_kernel(const float* __restrict__ vmv,
                              const float* __restrict__ vs,
                              unsigned short* __restrict__ dst)
{
    __shared__ unsigned short tile[64][DV];
    int blk = blockIdx.x;
    int h = blk >> 6;
    int n0 = (blk & 63) << 6;
    int t = threadIdx.x;
    #pragma unroll
    for (int it = 0; it < 16; ++it) {
        int v = t + it*256;
        int r = v >> 6;
        int sg = v & 63;
        float4 x = *(const float4*)(vmv + ((size_t)(h*NN + n0 + r))*256 + sg*4);
        tile[r][sg*4+0] = f2bf(x.x);
        tile[r][sg*4+1] = f2bf(x.y);
        tile[r][sg*4+2] = f2bf(x.z);
        tile[r][sg*4+3] = f2bf(x.w);
    }
    #pragma unroll
    for (int it = 0; it < 4; ++it) {
        int v = t + it*256;
        int r = v >> 4;
        int si = v & 15;
        tile[r][256 + si] = f2bf(vs[((size_t)(h*NN + n0 + r))*16 + si]);
    }
    __syncthreads();
    #pragma unroll
    for (int it = 0; it < 17; ++it) {
        int v = t + it*256;
        int dd = v >> 4;
        int sg = v & 15;
        ushort4 o;
        o.x = tile[sg*4+0][dd];
        o.y = tile[sg*4+1][dd];
        o.z = tile[sg*4+2][dd];
        o.w = tile[sg*4+3][dd];
        *(ushort4*)(dst + ((size_t)(h*DV + dd))*NN + n0 + sg*4) = o;
    }
}

// ---- stage 2: flash attention, BN=64, i8 ip-QKT, 3 barriers/step ----
__global__ __launch_bounds__(512, 1)
void attn_kernel(const signed char*    __restrict__ Qip,
                 const unsigned short* __restrict__ Qdx,
                 const signed char*    __restrict__ Kip,
                 const unsigned short* __restrict__ Kmx,
                 const unsigned short* __restrict__ Vt,
                 float* __restrict__ out)
{
    // bytes: kt 2x16384 [0,32768) | kmx 2x24576 [32768,81920) | vt 34816 [81920,116736) | pb 16384 [116736,133120)
    __shared__ __align__(128) unsigned short smem[66560];   // 133,120 B

    int blk = blockIdx.x;
    int sbk = ((blk & 7) << 5) | (blk >> 3);   // grid 256, bijective XCD swizzle; XCD x = head x
    int h = sbk >> 5;
    int q0 = (sbk & 31) * 128;
    int tid = threadIdx.x;
    int w = tid >> 6;
    int lane = tid & 63;
    int l15 = lane & 15;
    int l4 = lane >> 4;
    int l7l = l15 & 3;
    int l7h = (l15 >> 2) & 1;
    int x7 = l15 & 7;

    // Q ip fragments: i8, B-operand (col=q=l15, k=l4*16+e), 4 K=64 steps
    const signed char* qipr = Qip + (size_t)(h*NN + q0 + w*16 + l15) * DIP + l4*16;
    i32x4 qip[4];
    #pragma unroll
    for (int s = 0; s < 4; ++s) qip[s] = *(const i32x4*)(qipr + s*64);
    // Q dist fragments: bf16 (dup-block scheme)
    const unsigned short* qdxr = Qdx + (size_t)(h*NN + q0 + w*16 + l15) * DDX + l4*8;
    bf16x8 qdx[8];
    #pragma unroll
    for (int ks = 0; ks < 8; ++ks) qdx[ks] = *(const bf16x8*)(qdxr + ks*32);

    // LDS read bases (bytes)
    int cl16 = (l4 ^ l7l) * 16;
    int mA  = l15*384 + cl16 + l7h*64;
    int mB  = l15*384 + cl16 + 64 - l7h*64;
    int kti[4];
    #pragma unroll
    for (int s = 0; s < 4; ++s)
        kti[s] = l15*256 + (((s*4 + l4) ^ x7) << 4);
    int vb0 = (l15>>1)*256 + ((((l15&1)*8 + l4) ^ (l15>>1)) << 4);
    int vb1 = (l15>>1)*256 + ((((l15&1)*8 + 4 + l4) ^ (l15>>1)) << 4);
    int pbW = 116736 + w*2048 + l15*128;
    int pw[4];
    #pragma unroll
    for (int kt4 = 0; kt4 < 4; ++kt4)
        pw[kt4] = pbW + (((kt4*2 + (l4>>1)) ^ x7) << 4) + ((l4&1) << 3);
    int pr0 = pbW + ((l4 ^ x7) << 4);
    int pr1 = pbW + (((4+l4) ^ x7) << 4);

    // DMA source offsets, loop-invariant
    int kts0, kts1;                       // Kip bytes
    { int idx = tid;       int r_ = idx>>4, sg_ = idx&15; kts0 = r_*256 + ((sg_ ^ (r_&7))<<4); }
    { int idx = tid+512;   int r_ = idx>>4, sg_ = idx&15; kts1 = r_*256 + ((sg_ ^ (r_&7))<<4); }
    int kms0, kms1, kms2;                 // Kmx ush
#define KMFL(SLOT, DST) { int r_ = (SLOT)/24, fp_ = (SLOT)%24; \
    int g_ = fp_>>3, po_ = fp_&7; \
    int pl_ = ((((po_>>2)&1) ^ ((r_>>2)&1)) << 2) | ((po_&3) ^ (r_&3)); \
    DST = r_*DKM + (g_*8 + pl_)*8; }
    KMFL(tid, kms0) KMFL(tid+512, kms1) KMFL(tid+1024, kms2)
#undef KMFL
    int vts0, vts1, vts2, vts3, vts4;     // Vt ush
#define VTF(SLOT, DST) { int ch_ = (SLOT)>>4, ps_ = (SLOT)&15; int ls_ = ps_ ^ (ch_&7); \
    DST = (ch_*2 + (ls_>>3))*NN + (ls_&7)*8; }
    VTF(tid, vts0) VTF(tid+512, vts1) VTF(tid+1024, vts2) VTF(tid+1536, vts3) VTF(tid+2048, vts4)
#undef VTF

    const signed char*    kiph = Kip + (size_t)h*NN*DIP;
    const unsigned short* kmxh = Kmx + (size_t)h*NN*DKM;
    const unsigned short* vh   = Vt  + (size_t)h*DV*NN;

    f32x4 zero = {0.f, 0.f, 0.f, 0.f};
    i32x4 zi = {0, 0, 0, 0};
    f32x4 oacc[17];
    #pragma unroll
    for (int ct = 0; ct < 17; ++ct) oacc[ct] = zero;
    float mreg = -__builtin_inff();
    float lreg = 0.f;
    const float F = 0.08274443827037988f * (6.0f/127.0f) * (6.0f/127.0f);

    // K staging: 5 VMEM instr/wave (uniform). V staging: waves 0-1: 5, waves 2-7: 4.
#define ISSUE_K(TILE, BUF) do { \
    const signed char* ks_ = kiph + (size_t)(TILE)*BN*DIP; \
    const unsigned short* ms_ = kmxh + (size_t)(TILE)*BN*DKM; \
    char* ktd_ = (char*)smem + (BUF)*16384; \
    char* kmd_ = (char*)smem + 32768 + (BUF)*24576; \
    gload16(ks_ + kts0, ktd_ + tid*16); \
    gload16(ks_ + kts1, ktd_ + (tid+512)*16); \
    gload16(ms_ + kms0, kmd_ + tid*16); \
    gload16(ms_ + kms1, kmd_ + (tid+512)*16); \
    gload16(ms_ + kms2, kmd_ + (tid+1024)*16); \
} while (0)

#define ISSUE_V(TILE) do { \
    const unsigned short* vs_ = vh + (TILE)*BN; \
    char* vtd_ = (char*)smem + 81920; \
    gload16(vs_ + vts0, vtd_ + tid*16); \
    gload16(vs_ + vts1, vtd_ + (tid+512)*16); \
    gload16(vs_ + vts2, vtd_ + (tid+1024)*16); \
    gload16(vs_ + vts3, vtd_ + (tid+1536)*16); \
    if (tid < 128) gload16(vs_ + vts4, vtd_ + (tid+2048)*16); \
} while (0)

    ISSUE_K(0, 0);
    int cur = 0;
    #pragma unroll 1
    for (int t = 0; t < NT; ++t) {
        ISSUE_V(t);                          // vt free: BAR3(t-1) passed
        if (t < NT-1) {
            ISSUE_K(t+1, cur^1);             // kt/kmx(t-1) buffer free since QKT(t-1)
            // drain K(t) (oldest 5); keep V(t) 4|5 + K(t+1) 5 in flight
            if (w < 2) asm volatile("s_waitcnt vmcnt(10)" ::: "memory");
            else       asm volatile("s_waitcnt vmcnt(9)"  ::: "memory");
        } else {
            if (w < 2) asm volatile("s_waitcnt vmcnt(5)" ::: "memory");
            else       asm volatile("s_waitcnt vmcnt(4)" ::: "memory");
        }
        __builtin_amdgcn_sched_barrier(0);
        __builtin_amdgcn_s_barrier();        // BAR1: K tile t visible
        __builtin_amdgcn_sched_barrier(0);

        const char* ktb = (const char*)smem + cur*16384;
        const char* kmb = (const char*)smem + 32768 + cur*24576;

        f32x4 sf[4];
        i32x4 si[4];
        __builtin_amdgcn_s_setprio(1);
        #pragma unroll
        for (int kt4 = 0; kt4 < 4; ++kt4) {
            const char* kb = ktb + kt4*4096;
            i32x4 a = zi;
            a = MFMAI8(*(const i32x4*)(kb + kti[0]), qip[0], a);
            a = MFMAI8(*(const i32x4*)(kb + kti[1]), qip[1], a);
            a = MFMAI8(*(const i32x4*)(kb + kti[2]), qip[2], a);
            a = MFMAI8(*(const i32x4*)(kb + kti[3]), qip[3], a);
            si[kt4] = a;
            const char* kk = kmb + kt4*6144;
            bf16x8 ka0 = *(const bf16x8*)(kk + mA);
            bf16x8 ka1 = *(const bf16x8*)(kk + mB);
            bf16x8 ka2 = *(const bf16x8*)(kk + mA + 128);
            bf16x8 kb0 = *(const bf16x8*)(kk + mB + 128);
            bf16x8 kb1 = *(const bf16x8*)(kk + mA + 256);
            bf16x8 kb2 = *(const bf16x8*)(kk + mB + 256);
            f32x4 d = zero;
            d = MFMA16(ka0, qdx[0], d);
            d = MFMA16(ka1, qdx[1], d);
            d = MFMA16(ka2, qdx[2], d);
            d = MFMA16(kb0, qdx[3], d);
            d = MFMA16(kb1, qdx[4], d);
            d = MFMA16(kb2, qdx[5], d);
            d = MFMA16(ka0, qdx[3], d);
            d = MFMA16(ka1, qdx[6], d);
            d = MFMA16(kb0, qdx[0], d);
            d = MFMA16(kb1, qdx[7], d);
            sf[kt4] = d;
        }
        __builtin_amdgcn_s_setprio(0);

        // merge i8 + dist scores
        f32x4 sn[4];
        #pragma unroll
        for (int kt4 = 0; kt4 < 4; ++kt4) {
            sn[kt4][0] = sf[kt4][0] + F * (float)si[kt4][0];
            sn[kt4][1] = sf[kt4][1] + F * (float)si[kt4][1];
            sn[kt4][2] = sf[kt4][2] + F * (float)si[kt4][2];
            sn[kt4][3] = sf[kt4][3] + F * (float)si[kt4][3];
        }

        // online softmax over 64 keys, per-lane q=l15; defer-max THR=8 (log2 units)
        float pm = fmaxf(
            fmaxf(fmaxf(fmaxf(sn[0][0], sn[0][1]), fmaxf(sn[0][2], sn[0][3])),
                  fmaxf(fmaxf(sn[1][0], sn[1][1]), fmaxf(sn[1][2], sn[1][3]))),
            fmaxf(fmaxf(fmaxf(sn[2][0], sn[2][1]), fmaxf(sn[2][2], sn[2][3])),
                  fmaxf(fmaxf(sn[3][0], sn[3][1]), fmaxf(sn[3][2], sn[3][3]))));
        pm = fmaxf(pm, __shfl_xor(pm, 16, 64));
        pm = fmaxf(pm, __shfl_xor(pm, 32, 64));
        if (!__all(pm <= mreg + 8.0f)) {
            float mnew = fmaxf(mreg, pm);
            float al = fexp2(mreg - mnew);      // 0 on first tile
            mreg = mnew;
            lreg *= al;
            float a0 = __shfl(al, l4*4+0, 64);
            float a1 = __shfl(al, l4*4+1, 64);
            float a2 = __shfl(al, l4*4+2, 64);
            float a3 = __shfl(al, l4*4+3, 64);
            #pragma unroll
            for (int ct = 0; ct < 17; ++ct) {
                oacc[ct][0] *= a0; oacc[ct][1] *= a1;
                oacc[ct][2] *= a2; oacc[ct][3] *= a3;
            }
        }
        char* pbp = (char*)smem;
        #pragma unroll
        for (int kt4 = 0; kt4 < 4; ++kt4) {
            float p0 = fexp2(sn[kt4][0] - mreg), p1 = fexp2(sn[kt4][1] - mreg);
            float p2 = fexp2(sn[kt4][2] - mreg), p3 = fexp2(sn[kt4][3] - mreg);
            lreg += (p0 + p1) + (p2 + p3);
            unsigned r01, r23;
            asm("v_cvt_pk_bf16_f32 %0, %1, %2" : "=v"(r01) : "v"(p0), "v"(p1));
            asm("v_cvt_pk_bf16_f32 %0, %1, %2" : "=v"(r23) : "v"(p2), "v"(p3));
            unsigned long long pk = ((unsigned long long)r23 << 32) | (unsigned long long)r01;
            *(unsigned long long*)(pbp + pw[kt4]) = pk;
        }

        // drain V(t): remaining in flight = K(t+1) (5) or nothing on last iter
        if (t < NT-1) asm volatile("s_waitcnt vmcnt(5)" ::: "memory");
        else          asm volatile("s_waitcnt vmcnt(0)" ::: "memory");
        __builtin_amdgcn_sched_barrier(0);
        __builtin_amdgcn_s_barrier();        // BAR2: V tile + everyone's P ready
        __builtin_amdgcn_sched_barrier(0);

        // PV: O += P(16x64) @ V(64x272)
        {
            bf16x8 pa0 = *(const bf16x8*)(pbp + pr0);
            bf16x8 pa1 = *(const bf16x8*)(pbp + pr1);
            const char* vtb = (const char*)smem + 81920;
            __builtin_amdgcn_s_setprio(1);
            #pragma unroll
            for (int ct = 0; ct < 17; ++ct) {
                bf16x8 bv0 = *(const bf16x8*)(vtb + ct*2048 + vb0);
                oacc[ct] = MFMA16(pa0, bv0, oacc[ct]);
            }
            #pragma unroll
            for (int ct = 0; ct < 17; ++ct) {
                bf16x8 bv1 = *(const bf16x8*)(vtb + ct*2048 + vb1);
                oacc[ct] = MFMA16(pa1, bv1, oacc[ct]);
            }
            __builtin_amdgcn_s_setprio(0);
        }
        __builtin_amdgcn_s_barrier();        // BAR3: all waves done reading vt
        __builtin_amdgcn_sched_barrier(0);
        cur ^= 1;
    }
#undef ISSUE_K
#undef ISSUE_V

    // epilogue: finish deferred l, scatter
    float lf = lreg;
    lf += __shfl_xor(lf, 16, 64);
    lf += __shfl_xor(lf, 32, 64);
    const size_t mv_total = (size_t)HH * NN * 256;
    #pragma unroll
    for (int j = 0; j < 4; ++j) {
        float inv = 1.0f / __shfl(lf, l4*4 + j, 64);
        int q = q0 + w*16 + l4*4 + j;
        float* po = out + ((size_t)h*NN + q) * 256 + l15;
        #pragma unroll
        for (int ct = 0; ct < 16; ++ct)
            po[ct*16] = oacc[ct][j] * inv;
        out[mv_total + ((size_t)h*NN + q)*16 + l15] = oacc[16][j] * inv;
    }
}

extern "C" void kernel_launch(void* const* d_in, const int* in_sizes, int n_in,
                              void* d_out, int out_size, void* d_ws, size_t ws_size,
                              hipStream_t stream)
{
    const float* q_mv = (const float*)d_in[0];
    const float* k_mv = (const float*)d_in[1];
    const float* v_mv = (const float*)d_in[2];
    const float* q_s  = (const float*)d_in[3];
    const float* k_s  = (const float*)d_in[4];
    const float* v_s  = (const float*)d_in[5];
    const float* basis_q = (const float*)d_in[6];
    const float* basis_k = (const float*)d_in[7];
    float* out = (float*)d_out;

    signed char* qip8 = (signed char*)d_ws;                         // [8][4096][256] i8
    signed char* kip8 = qip8 + (size_t)HH*NN*DIP;                   // [8][4096][256] i8
    unsigned short* qdx = (unsigned short*)(kip8 + (size_t)HH*NN*DIP); // [8][4096][256] bf16
    unsigned short* kmx = qdx + (size_t)HH*NN*DDX;                  // [8][4096][192] bf16
    unsigned short* vt  = kmx + (size_t)HH*NN*DKM;                  // [8][272][4096] bf16
    // total ws use: ~64.1 MB

    // 1/sqrt(304) * log2(e): dist features carry it; ip carries it via F in-kernel
    const float qscale = 0.08274443827037988f;

    feat_kernel<<<dim3(1024), dim3(256), 0, stream>>>(q_mv, q_s, basis_q, qscale, 1, qip8, qdx);
    feat_kernel<<<dim3(1024), dim3(256), 0, stream>>>(k_mv, k_s, basis_k, 1.0f,   0, kip8, kmx);
    vtrans_kernel<<<dim3(512), dim3(256), 0, stream>>>(v_mv, v_s, vt);
    attn_kernel<<<dim3(256), dim3(512), 0, stream>>>(qip8, qdx, kip8, kmx, vt, out);
}